// Round 1
// baseline (883.333 us; speedup 1.0000x reference)
//
#include <hip/hip_runtime.h>
#include <math.h>

#define N_RES 768
#define DS 384
#define DP 128
#define DH 16
#define NH 12
#define PQ 4
#define PV 8
#define HC (NH*DH)              // 192
#define QP_RAW (NH*PQ*3)        // 144
#define KVP_RAW (NH*(PQ+PV)*3)  // 432
#define CATD (NH*(DP+DH+PV*4))  // 2112
#define BK 64
#define ZP 132                  // padded z row (floats); (4j+c)%32 spreads banks

// workspace float offsets
#define WS_Q   0
#define WS_K   (WS_Q + N_RES*HC)
#define WS_V   (WS_K + N_RES*HC)
#define WS_QP  (WS_V + N_RES*HC)            // [N][12][4][3]
#define WS_KP  (WS_QP + N_RES*NH*PQ*3)
#define WS_VP  (WS_KP + N_RES*NH*PQ*3)      // [N][12][8][3]
#define WS_CAT (WS_VP + N_RES*NH*PV*3)      // [N][2112]

// ---------------- kernel 1: input projections + frame apply ----------------
__global__ __launch_bounds__(256) void k_proj(
    const float* __restrict__ s, const float* __restrict__ rot,
    const float* __restrict__ trans,
    const float* __restrict__ Wq, const float* __restrict__ bq,
    const float* __restrict__ Wkv, const float* __restrict__ bkv,
    const float* __restrict__ Wqp, const float* __restrict__ bqp,
    const float* __restrict__ Wkvp, const float* __restrict__ bkvp,
    float* __restrict__ ws)
{
    __shared__ float s_s[8][DS];
    __shared__ float rq[8][QP_RAW];
    __shared__ float rkv[8][KVP_RAW];
    const int t = threadIdx.x;
    const int n0 = blockIdx.x * 8;

    for (int idx = t; idx < 8 * DS; idx += 256)
        s_s[idx / DS][idx % DS] = s[(n0 + idx / DS) * DS + idx % DS];
    __syncthreads();

    // 1152 output columns: [Wq 192 | Wkv 384 | Wqp 144 | Wkvp 432]
    for (int j = t; j < 1152; j += 256) {
        const float* W; int col, nc; float bias;
        if (j < 192)      { W = Wq;   col = j;       nc = 192; bias = bq[col]; }
        else if (j < 576) { W = Wkv;  col = j - 192; nc = 384; bias = bkv[col]; }
        else if (j < 720) { W = Wqp;  col = j - 576; nc = 144; bias = bqp[col]; }
        else              { W = Wkvp; col = j - 720; nc = 432; bias = bkvp[col]; }
        float acc[8];
        #pragma unroll
        for (int r = 0; r < 8; r++) acc[r] = bias;
        for (int i = 0; i < DS; i++) {
            float w = W[i * nc + col];
            #pragma unroll
            for (int r = 0; r < 8; r++) acc[r] += s_s[r][i] * w;
        }
        if (j < 192) {
            #pragma unroll
            for (int r = 0; r < 8; r++) ws[WS_Q + (n0 + r) * HC + j] = acc[r];
        } else if (j < 576) {
            int jj = j - 192, h = jj / 32, dd = jj % 32;
            if (dd < 16) {
                #pragma unroll
                for (int r = 0; r < 8; r++) ws[WS_K + (n0 + r) * HC + h * 16 + dd] = acc[r];
            } else {
                #pragma unroll
                for (int r = 0; r < 8; r++) ws[WS_V + (n0 + r) * HC + h * 16 + dd - 16] = acc[r];
            }
        } else if (j < 720) {
            #pragma unroll
            for (int r = 0; r < 8; r++) rq[r][j - 576] = acc[r];
        } else {
            #pragma unroll
            for (int r = 0; r < 8; r++) rkv[r][j - 720] = acc[r];
        }
    }
    __syncthreads();

    // frame apply: 8 rows * (48 qp + 144 kvp) points
    for (int idx = t; idx < 8 * 192; idx += 256) {
        int r = idx / 192, pi = idx % 192;
        int n = n0 + r;
        float x, y, zc; float* dst;
        if (pi < 48) {
            x = rq[r][pi]; y = rq[r][48 + pi]; zc = rq[r][96 + pi];
            dst = ws + WS_QP + n * (NH * PQ * 3) + pi * 3;
        } else {
            int p2 = pi - 48;
            x = rkv[r][p2]; y = rkv[r][144 + p2]; zc = rkv[r][288 + p2];
            int h = p2 / 12, pp = p2 % 12;
            if (pp < 4) dst = ws + WS_KP + n * (NH * PQ * 3) + (h * PQ + pp) * 3;
            else        dst = ws + WS_VP + n * (NH * PV * 3) + (h * PV + pp - 4) * 3;
        }
        const float* R = rot + n * 9;
        const float* T = trans + n * 3;
        dst[0] = R[0] * x + R[1] * y + R[2] * zc + T[0];
        dst[1] = R[3] * x + R[4] * y + R[5] * zc + T[1];
        dst[2] = R[6] * x + R[7] * y + R[8] * zc + T[2];
    }
}

// ---------------- kernel 2: fused IPA attention, one block per q row ----------------
__global__ __launch_bounds__(128) void k_attn(
    const float* __restrict__ z, const float* __restrict__ mask,
    const float* __restrict__ rot, const float* __restrict__ trans,
    const float* __restrict__ Wb, const float* __restrict__ bb,
    const float* __restrict__ hweights,
    float* __restrict__ ws)
{
    __shared__ float z_s[BK * ZP];        // 33 KB, swizzle-by-pad
    __shared__ float p_s[NH][68];
    __shared__ float Wb_s[NH][DP];
    __shared__ float q_s[HC];
    __shared__ float qpts_s[NH * PQ * 3];
    __shared__ float opts_s[NH * PV * 3];
    __shared__ float r_s[NH];
    __shared__ float inv_s[NH];
    __shared__ float rot_s[9], trans_s[3];

    const int t = threadIdx.x;
    const int lane = t & 63;
    const int w = t >> 6;     // wave 0/1; handles heads 6w..6w+5
    const int q = blockIdx.x;

    for (int i = t; i < HC; i += 128) q_s[i] = ws[WS_Q + q * HC + i];
    for (int i = t; i < NH * PQ * 3; i += 128) qpts_s[i] = ws[WS_QP + q * NH * PQ * 3 + i];
    for (int i = t; i < NH * DP; i += 128) {     // transpose Wb (128,12) -> [h][c]
        int c = i / NH, h = i % NH;
        Wb_s[h][c] = Wb[i];
    }
    if (t < 9) rot_s[t] = rot[q * 9 + t];
    if (t < 3) trans_s[t] = trans[q * 3 + t];

    float hw[6], bbv[6];
    #pragma unroll
    for (int hl = 0; hl < 6; hl++) {
        float x = hweights[w * 6 + hl];
        hw[hl] = log1pf(expf(x)) * 0.1360827635f;   // softplus * sqrt(1/54)
        bbv[hl] = bb[w * 6 + hl];
    }

    float m_run[6], ssum[6], r_run[6];
    float acc_z[6][2];
    #pragma unroll
    for (int hl = 0; hl < 6; hl++) {
        m_run[hl] = -1e30f; ssum[hl] = 0.f; r_run[hl] = 0.f;
        acc_z[hl][0] = 0.f; acc_z[hl][1] = 0.f;
    }
    float acc_o0 = 0.f, acc_o1 = 0.f;
    float acc_p0 = 0.f, acc_p1 = 0.f, acc_p2 = 0.f;

    const int h_o0 = lane >> 4;            // o mapping: idx = h*16+d
    const int h_o1 = 4 + (lane >> 4);      // valid only if < 6  (lane<32)
    const bool act_o1 = (h_o1 < 6);
    const int h_p0 = lane / 24;            // o_pts mapping: idx = h*24+(p*3+c)
    const int h_p1 = (lane + 64) / 24;
    const int h_p2 = (lane + 128) / 24;    // lane<16 only
    const bool act_p2 = (lane < 16);

    for (int kb = 0; kb < N_RES; kb += BK) {
        __syncthreads();   // prev iteration's consumers of z_s/p_s done
        {
            const float4* src = (const float4*)(z + (size_t)(q * N_RES + kb) * DP);
            for (int idx = t; idx < BK * 32; idx += 128) {
                int jj = idx >> 5, c4 = idx & 31;
                float4 v4 = src[jj * 32 + c4];
                *(float4*)&z_s[jj * ZP + c4 * 4] = v4;
            }
        }
        __syncthreads();

        // ---- logits for k = kb + lane, 6 heads ----
        const int kk = kb + lane;
        float logit[6];
        {
            float bacc[6];
            #pragma unroll
            for (int hl = 0; hl < 6; hl++) bacc[hl] = 0.f;
            for (int c4 = 0; c4 < 32; c4++) {
                float4 z4 = *(const float4*)&z_s[lane * ZP + c4 * 4];
                #pragma unroll
                for (int hl = 0; hl < 6; hl++) {
                    float4 w4 = *(const float4*)&Wb_s[w * 6 + hl][c4 * 4];
                    bacc[hl] += z4.x * w4.x + z4.y * w4.y + z4.z * w4.z + z4.w * w4.w;
                }
            }
            const float* krow = ws + WS_K + (size_t)kk * HC;
            const float* kprow = ws + WS_KP + (size_t)kk * NH * PQ * 3;
            float mval = mask[q * N_RES + kk];
            #pragma unroll
            for (int hl = 0; hl < 6; hl++) {
                int gh = w * 6 + hl;
                float qk = 0.f;
                #pragma unroll
                for (int d4 = 0; d4 < 4; d4++) {
                    float4 q4 = *(const float4*)&q_s[gh * 16 + d4 * 4];
                    float4 k4 = *(const float4*)&krow[gh * 16 + d4 * 4];
                    qk += q4.x * k4.x + q4.y * k4.y + q4.z * k4.z + q4.w * k4.w;
                }
                float d2 = 0.f;
                #pragma unroll
                for (int p4i = 0; p4i < 3; p4i++) {
                    float4 a = *(const float4*)&qpts_s[gh * 12 + p4i * 4];
                    float4 b = *(const float4*)&kprow[gh * 12 + p4i * 4];
                    float dx = a.x - b.x, dy = a.y - b.y, dz = a.z - b.z, dw = a.w - b.w;
                    d2 += dx * dx + dy * dy + dz * dz + dw * dw;
                }
                logit[hl] = qk * 0.1443375673f + (bacc[hl] + bbv[hl]) * 0.5773502692f
                            + mval - 0.5f * hw[hl] * d2;
            }
        }

        // ---- online softmax (per head, 64-lane reduce) ----
        #pragma unroll
        for (int hl = 0; hl < 6; hl++) {
            float lm = logit[hl];
            #pragma unroll
            for (int off = 32; off; off >>= 1) lm = fmaxf(lm, __shfl_xor(lm, off));
            float m_new = fmaxf(m_run[hl], lm);
            float rr = __expf(m_run[hl] - m_new);
            float p = __expf(logit[hl] - m_new);
            ssum[hl] = ssum[hl] * rr + p;
            p_s[w * 6 + hl][lane] = p;
            r_run[hl] = rr;
            m_run[hl] = m_new;
            r_s[w * 6 + hl] = rr;   // same value from all lanes
        }
        __syncthreads();

        // ---- accumulate o ----
        {
            acc_o0 *= r_s[w * 6 + h_o0];
            float rl2 = act_o1 ? r_s[w * 6 + h_o1] : 0.f;
            acc_o1 *= rl2;
            for (int j = 0; j < BK; j++) {
                int kj = kb + j;
                float pa = p_s[w * 6 + h_o0][j];
                acc_o0 += pa * ws[WS_V + (size_t)kj * HC + w * 96 + lane];
                if (act_o1) {
                    float pb = p_s[w * 6 + h_o1][j];
                    acc_o1 += pb * ws[WS_V + (size_t)kj * HC + w * 96 + 64 + lane];
                }
            }
        }
        // ---- accumulate o_pts (global frame) ----
        {
            acc_p0 *= r_s[w * 6 + h_p0];
            acc_p1 *= r_s[w * 6 + h_p1];
            float rp2 = act_p2 ? r_s[w * 6 + h_p2] : 0.f;
            acc_p2 *= rp2;
            for (int j = 0; j < BK; j++) {
                int kj = kb + j;
                const float* vb = ws + WS_VP + (size_t)kj * (NH * PV * 3) + w * 144;
                float pa = p_s[w * 6 + h_p0][j];
                float pb = p_s[w * 6 + h_p1][j];
                acc_p0 += pa * vb[lane];
                acc_p1 += pb * vb[lane + 64];
                if (act_p2) {
                    float pc_ = p_s[w * 6 + h_p2][j];
                    acc_p2 += pc_ * vb[lane + 128];
                }
            }
        }
        // ---- accumulate o_pair from staged z ----
        {
            #pragma unroll
            for (int hl = 0; hl < 6; hl++) {
                acc_z[hl][0] *= r_run[hl];
                acc_z[hl][1] *= r_run[hl];
            }
            for (int j = 0; j < BK; j++) {
                float z0 = z_s[j * ZP + lane];
                float z1 = z_s[j * ZP + 64 + lane];
                #pragma unroll
                for (int hl = 0; hl < 6; hl++) {
                    float pv = p_s[w * 6 + hl][j];
                    acc_z[hl][0] += pv * z0;
                    acc_z[hl][1] += pv * z1;
                }
            }
        }
    }

    // ---- final: denominators ----
    float inv[6];
    #pragma unroll
    for (int hl = 0; hl < 6; hl++) {
        float sv = ssum[hl];
        #pragma unroll
        for (int off = 32; off; off >>= 1) sv += __shfl_xor(sv, off);
        inv[hl] = 1.f / sv;
        inv_s[w * 6 + hl] = inv[hl];
    }
    __syncthreads();

    float* cat = ws + WS_CAT + (size_t)q * CATD;
    // o
    cat[w * 96 + lane] = acc_o0 * inv_s[w * 6 + h_o0];
    if (act_o1) cat[w * 96 + 64 + lane] = acc_o1 * inv_s[w * 6 + h_o1];
    // o_pts normalized, global frame -> LDS for gather
    opts_s[w * 144 + lane] = acc_p0 * inv_s[w * 6 + h_p0];
    opts_s[w * 144 + 64 + lane] = acc_p1 * inv_s[w * 6 + h_p1];
    if (act_p2) opts_s[w * 144 + 128 + lane] = acc_p2 * inv_s[w * 6 + h_p2];
    // o_pair
    #pragma unroll
    for (int hl = 0; hl < 6; hl++) {
        int gh = w * 6 + hl;
        cat[576 + gh * 128 + lane] = acc_z[hl][0] * inv[hl];
        cat[576 + gh * 128 + 64 + lane] = acc_z[hl][1] * inv[hl];
    }
    __syncthreads();

    // inverse frame + norm: t<96 -> (head, point)
    if (t < 96) {
        int gh = t >> 3, p = t & 7;
        float gx = opts_s[gh * 24 + p * 3 + 0] - trans_s[0];
        float gy = opts_s[gh * 24 + p * 3 + 1] - trans_s[1];
        float gz = opts_s[gh * 24 + p * 3 + 2] - trans_s[2];
        float lx = rot_s[0] * gx + rot_s[3] * gy + rot_s[6] * gz;
        float ly = rot_s[1] * gx + rot_s[4] * gy + rot_s[7] * gz;
        float lz = rot_s[2] * gx + rot_s[5] * gy + rot_s[8] * gz;
        cat[192 + t] = lx;
        cat[288 + t] = ly;
        cat[384 + t] = lz;
        cat[480 + t] = sqrtf(lx * lx + ly * ly + lz * lz + 1e-8f);
    }
}

// ---------------- kernel 3: cat @ Wout + bout ----------------
__global__ __launch_bounds__(384) void k_out(
    const float* __restrict__ ws, const float* __restrict__ Wout,
    const float* __restrict__ bout, float* __restrict__ out)
{
    __shared__ float cat_s[8][192];
    const int t = threadIdx.x;
    const int n0 = blockIdx.x * 8;
    float acc[8];
    #pragma unroll
    for (int r = 0; r < 8; r++) acc[r] = 0.f;
    for (int c0 = 0; c0 < CATD; c0 += 192) {
        __syncthreads();
        for (int idx = t; idx < 8 * 192; idx += 384)
            cat_s[idx / 192][idx % 192] =
                ws[WS_CAT + (size_t)(n0 + idx / 192) * CATD + c0 + idx % 192];
        __syncthreads();
        for (int i = 0; i < 192; i++) {
            float wv = Wout[(size_t)(c0 + i) * DS + t];
            #pragma unroll
            for (int r = 0; r < 8; r++) acc[r] += cat_s[r][i] * wv;
        }
    }
    float b = bout[t];
    #pragma unroll
    for (int r = 0; r < 8; r++) out[(size_t)(n0 + r) * DS + t] = acc[r] + b;
}

extern "C" void kernel_launch(void* const* d_in, const int* in_sizes, int n_in,
                              void* d_out, int out_size, void* d_ws, size_t ws_size,
                              hipStream_t stream)
{
    const float* s     = (const float*)d_in[0];
    const float* z     = (const float*)d_in[1];
    const float* mask  = (const float*)d_in[2];
    const float* rot   = (const float*)d_in[3];
    const float* trans = (const float*)d_in[4];
    const float* Wq    = (const float*)d_in[5];
    const float* bq    = (const float*)d_in[6];
    const float* Wkv   = (const float*)d_in[7];
    const float* bkv   = (const float*)d_in[8];
    const float* Wqp   = (const float*)d_in[9];
    const float* bqp   = (const float*)d_in[10];
    const float* Wkvp  = (const float*)d_in[11];
    const float* bkvp  = (const float*)d_in[12];
    const float* Wb    = (const float*)d_in[13];
    const float* bb    = (const float*)d_in[14];
    const float* hwt   = (const float*)d_in[15];
    const float* Wout  = (const float*)d_in[16];
    const float* bout  = (const float*)d_in[17];
    float* ws  = (float*)d_ws;
    float* out = (float*)d_out;

    hipLaunchKernelGGL(k_proj, dim3(96), dim3(256), 0, stream,
                       s, rot, trans, Wq, bq, Wkv, bkv, Wqp, bqp, Wkvp, bkvp, ws);
    hipLaunchKernelGGL(k_attn, dim3(768), dim3(128), 0, stream,
                       z, mask, rot, trans, Wb, bb, hwt, ws);
    hipLaunchKernelGGL(k_out, dim3(96), dim3(384), 0, stream,
                       ws, Wout, bout, out);
}